// Round 3
// baseline (11822.350 us; speedup 1.0000x reference)
//
#include <hip/hip_runtime.h>
#include <math.h>

#define TT 19
#define TPREV 10

typedef __attribute__((ext_vector_type(8))) short bf8v;
typedef __attribute__((ext_vector_type(4))) float f4v;
typedef __attribute__((ext_vector_type(16))) float f16v;

__device__ __forceinline__ float sigmoidf_(float x){ return 1.f/(1.f+expf(-x)); }
__device__ __forceinline__ unsigned short f2bf(float x){
    unsigned int u = __float_as_uint(x);
    u += 0x7FFFu + ((u>>16)&1u);
    return (unsigned short)(u>>16);
}
__device__ __forceinline__ float bf2f(unsigned short b){ return __uint_as_float(((unsigned int)b)<<16); }

// RULE (R4, keep forever): NEVER use the offset-immediate arg of
// global_load_lds — it corrupts the LDS destination address. offset=0 +
// explicit pointer arithmetic only.
#define GLDS(g, l) __builtin_amdgcn_global_load_lds( \
    (const __attribute__((address_space(1))) void*)(g),   \
    (__attribute__((address_space(3))) void*)(l), 16, 0, 0)

struct HSeg {
    const unsigned short* in;
    int cl;        // log2(Cin) of the input buffer layout (5,7,8)
    int c0;        // absolute ci base
    int nch;       // number of 32-ci chunks
    int tap0, ntaps, five;
};
struct HJob {
    const unsigned short* wt;   // tile stream
    float* out;
    int cout_stride, pad;
    HSeg s;
};
struct HJobs14 { HJob j[14]; };
struct HJobs9  { HJob j[9]; };

// ------------------------------------------------------------------
// hconvA: stream-path conv kernel, deep-pipelined (T2+T4+T5 combo).
//   N-tile 256 px (8 rows), M=128, 4 waves, wave tile 64x128 (2x4 of
//   32x32) -> 16 MFMA / 12 ds_read_b128 per tap per wave (0.75 rd/MFMA).
//   Weight pipeline: 4 x 8KB LDS buffers, GLDS issue at tap t targets
//   buf[(t+2)&3]; counted s_waitcnt vmcnt(4) (never 0 in steady state);
//   ONE s_barrier per tap.
//   Safety invariants (do not edit without re-deriving):
//   - buf[(t+2)&3] was last ds_read at tap t-2; those reads complete
//     before each wave's explicit lgkmcnt(0) preceding barrier A(t-1),
//     and the GLDS issue at t is after barrier A(t-1) in program order
//     for every wave -> no overwrite race with 1 barrier/tap.
//   - tile t completeness: own vmcnt(4) (outstanding = tiles t+1,t+2)
//     + barrier A(t) covers other waves' GLDS.
//   - sH restage happens only after a full __syncthreads() (drains).
//   - vmcnt ledger holds for any ntot>=2 (incl. lconv nch=8,ntaps=1:
//     traced t=0..7; waits 4/4.../2/0 retire exactly tile t).
//   sH G-slot XOR swizzle: cell stride 40 shorts (20 dw) makes lanes
//   {c,c+8,c+16,c+24} 4-way bank-alias; storing ci-group G at slot
//   G ^ ((cell>>3)&3) gives the 4 aliasing lanes 4 distinct 16B slots
//   -> conflict-free ds_read_b128. Swizzle applied on BOTH write (stage)
//   and read (baddr) sides.
// ------------------------------------------------------------------
template<typename JOBS>
__global__ __launch_bounds__(256, 2) void hconvA_kernel(JOBS jobs)
{
    __shared__ unsigned short sA[16384];   // 4 x 8KB weight tile buffers
    __shared__ unsigned short sH[19200];   // halo 12 rows x 40 cells x 40 shorts, swizzled
    const int tid = threadIdx.x;

    // XCD-clustered job mapping: bid%8 ~ XCD; give each XCD-class a
    // contiguous range of (job, xtile) so each XCD streams few weight
    // streams (L2-resident). Requires nb%8==0 and gridDim.x==32.
    const int nb   = gridDim.x * gridDim.y;
    const int per8 = nb >> 3;
    const int bidl = blockIdx.x + gridDim.x * blockIdx.y;
    const int g    = (bidl & 7) * per8 + (bidl >> 3);
    const int jy   = g >> 5;
    const int xt   = g & 31;
    const HJob jb = jobs.j[jy];

    const int ng0 = xt << 8;
    const int bb = ng0 >> 10, p0 = ng0 & 1023;
    const int y0 = p0 >> 5;          // {0,8,16,24}

    const int lane = tid & 63, wv = tid >> 6;
    const int wm = (wv & 1) << 6;    // M base 0/64
    const int wn = (wv >> 1) << 7;   // N base 0/128
    const int col = lane & 31, ll5 = lane >> 5;

    // tap-independent halo cell index per ni (local halo coords)
    int cell0[4];
#pragma unroll
    for (int ni = 0; ni < 4; ++ni) {
        const int ln = wn + ni * 32 + col;
        cell0[ni] = ((ln >> 5) + 2) * 40 + (ln & 31) + 4;
    }
    const int rowA0 = (wm + col) * 8;    // A-tile: + mi*256 + s*2048 + ll5*1024
    const int oA = ll5 * 1024;

    f16v acc[2][4];
#pragma unroll
    for (int i = 0; i < 2; ++i)
#pragma unroll
        for (int j = 0; j < 4; ++j) acc[i][j] = (f16v)0.f;

    const HSeg sg = jb.s;
    const unsigned short* inb = sg.in + ((size_t)bb << (10 + sg.cl));
    const unsigned short* wptr = jb.wt;
    const int ntaps = sg.ntaps;
    const int ntot = sg.nch * ntaps;

    // ---- stage chunk 0 halo (1920 16B slots, swizzled) ----
    {
        const int c0 = sg.c0;
#pragma unroll
        for (int k = 0; k < 8; ++k) {
            const int s = tid + k * 256;
            if (s < 1920) {
                const int r = s / 160;
                const int rem = s - r * 160;
                const int cc = rem >> 2, G = rem & 3;
                const int y = y0 + r - 2, x = cc - 4;
                const bool okv = ((unsigned)y < 32u) & ((unsigned)x < 32u);
                const int yc = okv ? y : 0, xc = okv ? x : 0;
                bf8v v = *(const bf8v*)(inb + ((((yc << 5) + xc)) << sg.cl) + c0 + G * 8);
                if (!okv) v = (bf8v)(short)0;
                const int cell = r * 40 + cc;
                *(bf8v*)&sH[cell * 40 + ((G ^ ((cell >> 3) & 3))) * 8] = v;
            }
        }
    }
    // ---- prologue: issue tiles 0,1 into buf0,buf1 ----
    GLDS(wptr + tid * 8,                &sA[tid * 8]);
    GLDS(wptr + (tid + 256) * 8,        &sA[(tid + 256) * 8]);
    GLDS(wptr + 4096 + tid * 8,         &sA[4096 + tid * 8]);
    GLDS(wptr + 4096 + (tid + 256) * 8, &sA[4096 + (tid + 256) * 8]);
    wptr += 8192;

    int bcur = 0, tc = 0, ch = 0;
    for (int t = 0; t < ntot; ++t) {
        if (tc == ntaps) {
            tc = 0; ++ch;
            __syncthreads();   // all waves done reading sH (full drain)
            const int c0 = sg.c0 + ch * 32;
#pragma unroll
            for (int k = 0; k < 8; ++k) {
                const int s = tid + k * 256;
                if (s < 1920) {
                    const int r = s / 160;
                    const int rem = s - r * 160;
                    const int cc = rem >> 2, G = rem & 3;
                    const int y = y0 + r - 2, x = cc - 4;
                    const bool okv = ((unsigned)y < 32u) & ((unsigned)x < 32u);
                    const int yc = okv ? y : 0, xc = okv ? x : 0;
                    bf8v v = *(const bf8v*)(inb + ((((yc << 5) + xc)) << sg.cl) + c0 + G * 8);
                    if (!okv) v = (bf8v)(short)0;
                    const int cell = r * 40 + cc;
                    *(bf8v*)&sH[cell * 40 + ((G ^ ((cell >> 3) & 3))) * 8] = v;
                }
            }
        }
        // issue tile t+2 into buf[(bcur+2)&3]
        if (t + 2 < ntot) {
            const int b2 = (bcur + 2) & 3;
            GLDS(wptr + tid * 8,         &sA[b2 * 4096 + tid * 8]);
            GLDS(wptr + (tid + 256) * 8, &sA[b2 * 4096 + (tid + 256) * 8]);
            wptr += 4096;
        }
        // swizzled B addresses for this tap
        int tapofs = 0;
        if (sg.five) {
            const int tap = sg.tap0 + tc;
            const int t5 = (tap * 52) >> 8;
            tapofs = (t5 - 2) * 40 + (tap - t5 * 5 - 2);
        }
        int baddr[4][2];
#pragma unroll
        for (int ni = 0; ni < 4; ++ni) {
            const int cT = cell0[ni] + tapofs;
            const int key = (cT >> 3) & 3;
            const int cb = cT * 40;
#pragma unroll
            for (int s = 0; s < 2; ++s)
                baddr[ni][s] = cb + (((s << 1) + ll5) ^ key) * 8;
        }
        // counted waits: own tile-t loads (oldest) done; lgkmcnt(0) makes
        // own ds_writes (stage taps) visible before the barrier.
        if (t + 2 < ntot)      asm volatile("s_waitcnt vmcnt(4) lgkmcnt(0)" ::: "memory");
        else if (t + 1 < ntot) asm volatile("s_waitcnt vmcnt(2) lgkmcnt(0)" ::: "memory");
        else                   asm volatile("s_waitcnt vmcnt(0) lgkmcnt(0)" ::: "memory");
        __builtin_amdgcn_s_barrier();          // barrier A(t)
        __builtin_amdgcn_sched_barrier(0);

        const unsigned short* sAb = &sA[bcur * 4096];
        bf8v av[2][2], bv[2][4];
#pragma unroll
        for (int s = 0; s < 2; ++s) {
#pragma unroll
            for (int mi = 0; mi < 2; ++mi)
                av[s][mi] = *(const bf8v*)&sAb[s * 2048 + oA + rowA0 + mi * 256];
#pragma unroll
            for (int ni = 0; ni < 4; ++ni)
                bv[s][ni] = *(const bf8v*)&sH[baddr[ni][s]];
        }
        __builtin_amdgcn_s_setprio(1);
#pragma unroll
        for (int s = 0; s < 2; ++s)
#pragma unroll
            for (int mi = 0; mi < 2; ++mi)
#pragma unroll
                for (int ni = 0; ni < 4; ++ni)
                    acc[mi][ni] = __builtin_amdgcn_mfma_f32_32x32x16_bf16(
                        av[s][mi], bv[s][ni], acc[mi][ni], 0, 0, 0);
        __builtin_amdgcn_s_setprio(0);
        __builtin_amdgcn_sched_barrier(0);

        bcur = (bcur + 1) & 3;
        ++tc;
    }

    // epilogue (32x32 C/D): col=lane&31, row=(reg&3)+8*(reg>>2)+4*ll5
    const int nfix = ng0 + wn + col;
#pragma unroll
    for (int ni = 0; ni < 4; ++ni) {
        const int n = nfix + ni * 32;
        float* ob = jb.out + (size_t)n * jb.cout_stride;
#pragma unroll
        for (int mi = 0; mi < 2; ++mi) {
            const int mb = wm + mi * 32 + 4 * ll5;
            const f16v a = acc[mi][ni];
#pragma unroll
            for (int qd = 0; qd < 4; ++qd) {
                f4v v;
                v[0] = a[qd * 4 + 0]; v[1] = a[qd * 4 + 1];
                v[2] = a[qd * 4 + 2]; v[3] = a[qd * 4 + 3];
                *(f4v*)(ob + mb + qd * 8) = v;
            }
        }
    }
}

// ------------------------------------------------------------------
// packT: OIHW f32 -> linear tile stream [at][oct][row][8] bf16.
// ciMax: weights with ci >= ciMax are packed as zero (l0 x-conv pads
// Cin=16 up to a 32-ci chunk; matching halo channels are also zero).
// ------------------------------------------------------------------
__global__ __launch_bounds__(256) void packT_kernel(
    const float* __restrict__ src, unsigned short* __restrict__ dst,
    int Cin, int srcTaps, int rowOff, int ci0, int ntaps, int tap0,
    int ciMax, int total)
{
    const int idx = blockIdx.x * 256 + threadIdx.x;
    if (idx >= total) return;
    const int j = idx & 7;
    const int row = (idx >> 3) & 127;
    const int q = (idx >> 10) & 3;
    const int at = idx >> 12;
    const int ch = at / ntaps;
    const int tap = tap0 + (at - ch * ntaps);
    const int ci = ci0 + ch * 32 + q * 8 + j;
    float v = 0.f;
    if (ci < ciMax)
        v = src[((size_t)(rowOff + row) * Cin + ci) * srcTaps + tap];
    dst[idx] = f2bf(v);
}

// net (blended frame) written 32-channel-wide, upper 16 channels zero,
// so the l0 x-conv runs on the standard 32-ci stream path.
__global__ __launch_bounds__(256) void net_kernel(
    const float* __restrict__ frames, const float* __restrict__ mask,
    const float* __restrict__ xgen, unsigned short* __restrict__ net, int t)
{
    const int idx = blockIdx.x * 256 + threadIdx.x;  // 8192*32
    const int n = idx >> 5, ch = idx & 31;
    float v = 0.f;
    if (ch < 16) {
        const int b = n >> 10, p = n & 1023;
        const float fr = frames[((((size_t)b * 20 + t) << 10) + p) * 16 + ch];
        if (t < TPREV) v = fr;
        else {
            const float mk = mask[((((size_t)b * 9 + (t - TPREV)) << 10) + p) * 16 + ch];
            v = mk * fr + (1.f - mk) * xgen[(size_t)n * 16 + ch];
        }
    }
    net[idx] = f2bf(v);
}

__global__ __launch_bounds__(256) void gates_kernel(
    const float* __restrict__ preA, const float* __restrict__ preB,
    float* __restrict__ c, float* __restrict__ m,
    unsigned short* __restrict__ m_bf, unsigned short* __restrict__ mem)
{
    const int idx = blockIdx.x * 256 + threadIdx.x;  // 8192*128
    const int n = idx >> 7, ch = idx & 127;
    const float* pa = preA + (size_t)n * 896 + ch;
    const float* pb = preB + (size_t)n * 896 + ch;
    const float i_ = pa[0]   + pb[0];
    const float f_ = pa[128] + pb[128];
    const float g_ = pa[256] + pb[256];
    const float ip = pa[384] + pb[384];
    const float fp = pa[512] + pb[512];
    const float gp = pa[640] + pb[640];
    const float cn = sigmoidf_(f_ + 1.f) * c[idx] + sigmoidf_(i_) * tanhf(g_);
    const float mn = sigmoidf_(fp + 1.f) * m[idx] + sigmoidf_(ip) * tanhf(gp);
    c[idx] = cn;
    m[idx] = mn;
    m_bf[idx] = f2bf(mn);
    mem[(size_t)n * 256 + ch] = f2bf(cn);
    mem[(size_t)n * 256 + 128 + ch] = f2bf(mn);
}

__global__ __launch_bounds__(256) void hout_kernel(
    const float* __restrict__ preA, const float* __restrict__ preB,
    const float* __restrict__ opart, const float* __restrict__ lconv,
    unsigned short* __restrict__ h)
{
    const int idx = blockIdx.x * 256 + threadIdx.x;  // 8192*128
    const int n = idx >> 7, ch = idx & 127;
    float oc = preA[(size_t)n * 896 + 768 + ch] + preB[(size_t)n * 896 + 768 + ch];
#pragma unroll
    for (int j = 0; j < 8; ++j) oc += opart[idx + (size_t)j * 1048576];
    h[idx] = f2bf(sigmoidf_(oc) * tanhf(lconv[idx]));
}

__global__ __launch_bounds__(256) void wout_kernel(
    const unsigned short* __restrict__ h3, const float* __restrict__ wo,
    float* __restrict__ xgen, float* __restrict__ out, int t)
{
    const int idx = blockIdx.x * 256 + threadIdx.x;  // 8192*16
    const int n = idx >> 4, ch = idx & 15;
    const int b = n >> 10, p = n & 1023;
    const unsigned short* hr = h3 + (size_t)n * 128;
    const float* wr = wo + ch * 128;
    float acc = 0.f;
#pragma unroll 8
    for (int ci = 0; ci < 128; ++ci)
        acc = fmaf(bf2f(hr[ci]), wr[ci], acc);
    xgen[idx] = acc;
    out[((((size_t)b * TT + t) << 10) + p) * 16 + ch] = acc;
}

extern "C" void kernel_launch(void* const* d_in, const int* in_sizes, int n_in,
                              void* d_out, int out_size, void* d_ws, size_t ws_size,
                              hipStream_t stream)
{
    const float* frames = (const float*)d_in[0];
    const float* mask   = (const float*)d_in[1];
    const float* Wx0    = (const float*)d_in[2];
    const float* Wx     = (const float*)d_in[3];
    const float* Wh     = (const float*)d_in[4];
    const float* Wm     = (const float*)d_in[5];
    const float* Wo     = (const float*)d_in[6];
    const float* Wl     = (const float*)d_in[7];
    const float* Wout   = (const float*)d_in[8];
    float* out = (float*)d_out;

    char* base = (char*)d_ws;
    size_t off = 0;
    auto take = [&](size_t bytes) -> char* {
        char* p = base + off;
        off = (off + bytes + 255) & ~(size_t)255;
        return p;
    };
    // ---- zero-init region ----
    float* c0            = (float*)take(4ull * 1048576 * 4);
    float* m32           = (float*)take((size_t)1048576 * 4);
    unsigned short* hbf  = (unsigned short*)take(4ull * 1048576 * 2);
    unsigned short* mbf  = (unsigned short*)take((size_t)1048576 * 2);
    const size_t zbytes = off;
    // ---- working buffers ----
    float* xgen          = (float*)take((size_t)131072 * 4);
    float* preA          = (float*)take((size_t)8192 * 896 * 4);
    float* preB          = (float*)take((size_t)8192 * 896 * 4);
    float* lconv         = (float*)take((size_t)1048576 * 4);
    float* opart         = (float*)take(8ull * 1048576 * 4);
    unsigned short* net  = (unsigned short*)take((size_t)262144 * 2);   // [8192][32]
    unsigned short* mem  = (unsigned short*)take((size_t)2097152 * 2);
    // ---- packed weights (tile streams; +4096 el pad) ----
    unsigned short* pa0xT = (unsigned short*)take(((size_t)7 * 25 * 4096 + 4096) * 2);
    unsigned short* paT0 = (unsigned short*)take(((size_t)7 * 100 * 4096 + 4096) * 2);
    unsigned short* paT1 = (unsigned short*)take(((size_t)7 * 200 * 4096 + 4096) * 2);
    unsigned short* paT2 = (unsigned short*)take(((size_t)7 * 200 * 4096 + 4096) * 2);
    unsigned short* paT3 = (unsigned short*)take(((size_t)7 * 200 * 4096 + 4096) * 2);
    unsigned short* paT[4] = { paT0, paT1, paT2, paT3 };
    unsigned short* oT   = (unsigned short*)take((4ull * 200 * 4096 + 4096) * 2);
    unsigned short* lT   = (unsigned short*)take((4ull * 8 * 4096 + 4096) * 2);

    hipMemsetAsync(d_ws, 0, zbytes, stream);

    auto packT = [&](const float* s, unsigned short* d, int Cin, int srcTaps,
                     int rowOff, int ci0, int nch, int ntaps, int tap0, int ciMax) {
        const int total = nch * ntaps * 4096;
        packT_kernel<<<(total + 255) / 256, 256, 0, stream>>>(
            s, d, Cin, srcTaps, rowOff, ci0, ntaps, tap0, ciMax, total);
    };
    const int CIMAXBIG = 1 << 30;
    for (int g = 0; g < 7; ++g) {
        // l0 x-conv: Cin=16 zero-padded to one 32-ci chunk (25 tiles/group)
        packT(Wx0, pa0xT + (size_t)g * 25 * 4096, 16, 25, g * 128, 0, 1, 25, 0, 16);
        const float* hm0 = (g < 3) ? (Wh + (size_t)g * 128 * 128 * 25)
                         : (g == 6) ? (Wh + (size_t)384 * 128 * 25)
                                    : (Wm + (size_t)(g - 3) * 128 * 128 * 25);
        packT(hm0, paT0 + (size_t)g * 100 * 4096, 128, 25, 0, 0, 4, 25, 0, CIMAXBIG);
        for (int l = 1; l < 4; ++l) {
            packT(Wx + (size_t)(l - 1) * 896 * 128 * 25,
                  paT[l] + (size_t)g * 200 * 4096, 128, 25, g * 128, 0, 4, 25, 0, CIMAXBIG);
            const float* hmsrc = (g < 3) ? (Wh + ((size_t)l * 512 + g * 128) * 128 * 25)
                               : (g == 6) ? (Wh + ((size_t)l * 512 + 384) * 128 * 25)
                                          : (Wm + ((size_t)l * 384 + (g - 3) * 128) * 128 * 25);
            packT(hmsrc, paT[l] + ((size_t)g * 200 + 100) * 4096, 128, 25, 0, 0, 4, 25, 0, CIMAXBIG);
        }
    }
    for (int l = 0; l < 4; ++l) {
        packT(Wo + (size_t)l * 128 * 256 * 25, oT + (size_t)l * 200 * 4096,
              256, 25, 0, 0, 8, 25, 0, CIMAXBIG);
        packT(Wl + (size_t)l * 128 * 256, lT + (size_t)l * 8 * 4096,
              256, 1, 0, 0, 8, 1, 0, CIMAXBIG);
    }

    for (int t = 0; t < TT; ++t) {
        net_kernel<<<1024, 256, 0, stream>>>(frames, mask, xgen, net, t);
        for (int l = 0; l < 4; ++l) {
            unsigned short* hl = hbf + (size_t)l * 1048576;
            // ---- phase A: one hconvA dispatch of 14 jobs ----
            HJobs14 JA{};
            if (l == 0) {
                // interleave short x-jobs (25 taps) with long hm-jobs (100
                // taps) so each XCD-cluster gets a balanced mix.
                for (int g = 0; g < 7; ++g) {
                    const unsigned short* hmsrc = (g < 3 || g == 6) ? hl : mbf;
                    JA.j[2 * g] = HJob{ pa0xT + (size_t)g * 25 * 4096, preA + g * 128,
                                        896, 0, HSeg{ net, 5, 0, 1, 0, 25, 1 } };
                    JA.j[2 * g + 1] = HJob{ paT0 + (size_t)g * 100 * 4096, preB + g * 128,
                                            896, 0, HSeg{ hmsrc, 7, 0, 4, 0, 25, 1 } };
                }
            } else {
                for (int g = 0; g < 7; ++g) {
                    const unsigned short* hmsrc = (g < 3 || g == 6) ? hl : mbf;
                    JA.j[g] = HJob{ paT[l] + (size_t)g * 200 * 4096, preA + g * 128,
                                    896, 0, HSeg{ hbf + (size_t)(l - 1) * 1048576, 7, 0, 4, 0, 25, 1 } };
                    JA.j[7 + g] = HJob{ paT[l] + ((size_t)g * 200 + 100) * 4096, preB + g * 128,
                                        896, 0, HSeg{ hmsrc, 7, 0, 4, 0, 25, 1 } };
                }
            }
            hconvA_kernel<HJobs14><<<dim3(32, 14), 256, 0, stream>>>(JA);

            gates_kernel<<<4096, 256, 0, stream>>>(preA, preB,
                c0 + (size_t)l * 1048576, m32, mbf, mem);

            // ---- phase B: o-conv split by ci-chunk x8 + lconv (pipelined)
            HJobs9 JB{};
            for (int jj = 0; jj < 8; ++jj)
                JB.j[jj] = HJob{ oT + ((size_t)l * 200 + jj * 25) * 4096,
                                 opart + (size_t)jj * 1048576, 128, 0,
                                 HSeg{ mem, 8, jj * 32, 1, 0, 25, 1 } };
            JB.j[8] = HJob{ lT + (size_t)l * 8 * 4096, lconv, 128, 0,
                            HSeg{ mem, 8, 0, 8, 0, 1, 0 } };
            hconvA_kernel<HJobs9><<<dim3(32, 9), 256, 0, stream>>>(JB);

            hout_kernel<<<4096, 256, 0, stream>>>(preA, preB, opart, lconv, hl);
        }
        wout_kernel<<<512, 256, 0, stream>>>(hbf + (size_t)3 * 1048576, Wout, xgen, out, t);
    }
}

// Round 4
// 10913.453 us; speedup vs baseline: 1.0833x; 1.0833x over previous
//
#include <hip/hip_runtime.h>
#include <math.h>

#define TT 19
#define TPREV 10

typedef __attribute__((ext_vector_type(8))) short bf8v;
typedef __attribute__((ext_vector_type(4))) float f4v;
typedef __attribute__((ext_vector_type(16))) float f16v;

__device__ __forceinline__ float sigmoidf_(float x){ return 1.f/(1.f+expf(-x)); }
__device__ __forceinline__ unsigned short f2bf(float x){
    unsigned int u = __float_as_uint(x);
    u += 0x7FFFu + ((u>>16)&1u);
    return (unsigned short)(u>>16);
}
__device__ __forceinline__ float bf2f(unsigned short b){ return __uint_as_float(((unsigned int)b)<<16); }

// RULE (R4, keep forever): NEVER use the offset-immediate arg of
// global_load_lds — it corrupts the LDS destination address. offset=0 +
// explicit pointer arithmetic only.
#define GLDS(g, l) __builtin_amdgcn_global_load_lds( \
    (const __attribute__((address_space(1))) void*)(g),   \
    (__attribute__((address_space(3))) void*)(l), 16, 0, 0)

struct HSeg {
    const unsigned short* in;
    int cl;        // log2(Cin) of the input buffer layout (5,7,8)
    int c0;        // absolute ci base
    int nch;       // number of 32-ci chunks
    int tap0, ntaps, five;
};
struct HJob {
    const unsigned short* wt;   // tile stream
    float* out;
    int cout_stride, pad;
    HSeg s;
};
struct HJobs14 { HJob j[14]; };
struct HJobs9  { HJob j[9]; };

// ------------------------------------------------------------------
// sH PLANE LAYOUT (R4 fix for 8.7M bank conflicts measured in R3):
// halo stored as 4 ci-octet planes, each [cell][8 shorts]. A B-read
// (fixed oct o=2s+ll5) is lane-addr = plane(o) + (c + col)*16B ->
// 16B/lane stride, any 8 consecutive lanes cover 32 consecutive dwords
// = all 32 banks exactly once -> conflict-free for ANY base alignment
// (identical structure to the A-tile reads). No swizzle, no padding.
// Staging writes (G fastest across tid) are 2-way conflicted = free.
// ------------------------------------------------------------------

// ------------------------------------------------------------------
// hconvA: phase-A conv kernel, deep-pipelined (counted vmcnt + setprio).
//   N-tile 256 px (8 rows), M=128, 4 waves, wave tile 64x128 (2x4 of
//   32x32) -> 16 MFMA / 12 ds_read_b128 per tap per wave.
//   Weight pipeline: 4 x 8KB LDS buffers, GLDS issue at tap t targets
//   buf[(t+2)&3]; counted s_waitcnt vmcnt(4) (never 0 in steady state);
//   ONE s_barrier per tap.
//   Safety invariants (do not edit without re-deriving):
//   - buf[(t+2)&3] was last ds_read at tap t-2; those reads complete
//     before each wave's explicit lgkmcnt(0) preceding barrier A(t-1),
//     and the GLDS issue at t is after barrier A(t-1) in program order
//     for every wave -> no overwrite race with 1 barrier/tap.
//   - tile t completeness: own vmcnt(4) (outstanding = tiles t+1,t+2)
//     + barrier A(t) covers other waves' GLDS.
//   - sH restage happens only after a full __syncthreads() (drains the
//     GLDS queue; ledger restarts clean, still consistent).
//   - asm "memory" clobber fences all LDS/global ops each tap; the
//     MFMA cluster has no trailing sched_barrier so next-tap VALU/GLDS
//     issue may overlap the MFMA tail (register-only reordering safe).
// ------------------------------------------------------------------
template<typename JOBS>
__global__ __launch_bounds__(256, 2) void hconvA_kernel(JOBS jobs)
{
    __shared__ unsigned short sA[16384];   // 4 x 8KB weight tile buffers
    __shared__ unsigned short sH[15360];   // 4 planes x 480 cells x 8 shorts
    const int tid = threadIdx.x;

    // XCD-clustered job mapping: bid%8 ~ XCD; each XCD-class gets a
    // contiguous (job, xtile) range so it streams few weight streams
    // (L2-resident). Requires nb%8==0 and gridDim.x==32.
    const int nb   = gridDim.x * gridDim.y;
    const int per8 = nb >> 3;
    const int bidl = blockIdx.x + gridDim.x * blockIdx.y;
    const int g    = (bidl & 7) * per8 + (bidl >> 3);
    const int jy   = g >> 5;
    const int xt   = g & 31;
    const HJob jb = jobs.j[jy];

    const int ng0 = xt << 8;
    const int bb = ng0 >> 10, p0 = ng0 & 1023;
    const int y0 = p0 >> 5;          // {0,8,16,24}

    const int lane = tid & 63, wv = tid >> 6;
    const int wm = (wv & 1) << 6;    // M base 0/64
    const int wn = (wv >> 1) << 7;   // N base 0/128
    const int col = lane & 31, ll5 = lane >> 5;

    // tap-independent per-ni base: cell*8 + plane(ll5)*3840
    int bofs0[4];
#pragma unroll
    for (int ni = 0; ni < 4; ++ni) {
        const int ln = wn + ni * 32 + col;
        const int cell = ((ln >> 5) + 2) * 40 + (ln & 31) + 4;
        bofs0[ni] = cell * 8 + ll5 * 3840;
    }
    const int rowA0 = (wm + col) * 8;    // A-tile: + mi*256 + s*2048 + ll5*1024
    const int oA = ll5 * 1024;

    f16v acc[2][4];
#pragma unroll
    for (int i = 0; i < 2; ++i)
#pragma unroll
        for (int j = 0; j < 4; ++j) acc[i][j] = (f16v)0.f;

    const HSeg sg = jb.s;
    const unsigned short* inb = sg.in + ((size_t)bb << (10 + sg.cl));
    const unsigned short* wptr = jb.wt;
    const int ntaps = sg.ntaps;
    const int ntot = sg.nch * ntaps;

    // ---- stage chunk 0 halo (1920 16B slots: 480 cells x 4 octs) ----
    {
        const int c0 = sg.c0;
#pragma unroll
        for (int k = 0; k < 8; ++k) {
            const int s = tid + k * 256;
            if (s < 1920) {
                const int r = s / 160;
                const int rem = s - r * 160;
                const int cc = rem >> 2, G = rem & 3;
                const int y = y0 + r - 2, x = cc - 4;
                const bool okv = ((unsigned)y < 32u) & ((unsigned)x < 32u);
                const int yc = okv ? y : 0, xc = okv ? x : 0;
                bf8v v = *(const bf8v*)(inb + ((((yc << 5) + xc)) << sg.cl) + c0 + G * 8);
                if (!okv) v = (bf8v)(short)0;
                *(bf8v*)&sH[(G * 480 + r * 40 + cc) * 8] = v;
            }
        }
    }
    // ---- prologue: issue tiles 0,1 into buf0,buf1 ----
    GLDS(wptr + tid * 8,                &sA[tid * 8]);
    GLDS(wptr + (tid + 256) * 8,        &sA[(tid + 256) * 8]);
    GLDS(wptr + 4096 + tid * 8,         &sA[4096 + tid * 8]);
    GLDS(wptr + 4096 + (tid + 256) * 8, &sA[4096 + (tid + 256) * 8]);
    wptr += 8192;

    int bcur = 0, tc = 0, ch = 0;
    for (int t = 0; t < ntot; ++t) {
        if (tc == ntaps) {
            tc = 0; ++ch;
            __syncthreads();   // all waves done reading sH (full drain)
            const int c0 = sg.c0 + ch * 32;
#pragma unroll
            for (int k = 0; k < 8; ++k) {
                const int s = tid + k * 256;
                if (s < 1920) {
                    const int r = s / 160;
                    const int rem = s - r * 160;
                    const int cc = rem >> 2, G = rem & 3;
                    const int y = y0 + r - 2, x = cc - 4;
                    const bool okv = ((unsigned)y < 32u) & ((unsigned)x < 32u);
                    const int yc = okv ? y : 0, xc = okv ? x : 0;
                    bf8v v = *(const bf8v*)(inb + ((((yc << 5) + xc)) << sg.cl) + c0 + G * 8);
                    if (!okv) v = (bf8v)(short)0;
                    *(bf8v*)&sH[(G * 480 + r * 40 + cc) * 8] = v;
                }
            }
        }
        // issue tile t+2 into buf[(bcur+2)&3]
        if (t + 2 < ntot) {
            const int b2 = (bcur + 2) & 3;
            GLDS(wptr + tid * 8,         &sA[b2 * 4096 + tid * 8]);
            GLDS(wptr + (tid + 256) * 8, &sA[b2 * 4096 + (tid + 256) * 8]);
            wptr += 4096;
        }
        // cell offset for this tap (cell units; *8 shorts for addr)
        int tO = 0;
        if (sg.five) {
            const int tap = sg.tap0 + tc;
            const int t5 = (tap * 52) >> 8;
            tO = ((t5 - 2) * 40 + (tap - t5 * 5 - 2)) * 8;
        }
        // counted waits: own tile-t loads (oldest) done; lgkmcnt(0) makes
        // own ds_writes (stage taps) visible before the barrier.
        if (t + 2 < ntot)      asm volatile("s_waitcnt vmcnt(4) lgkmcnt(0)" ::: "memory");
        else if (t + 1 < ntot) asm volatile("s_waitcnt vmcnt(2) lgkmcnt(0)" ::: "memory");
        else                   asm volatile("s_waitcnt vmcnt(0) lgkmcnt(0)" ::: "memory");
        __builtin_amdgcn_s_barrier();          // barrier A(t)
        __builtin_amdgcn_sched_barrier(0);

        const unsigned short* sAb = &sA[bcur * 4096];
        bf8v av[2][2], bv[2][4];
#pragma unroll
        for (int s = 0; s < 2; ++s) {
#pragma unroll
            for (int mi = 0; mi < 2; ++mi)
                av[s][mi] = *(const bf8v*)&sAb[s * 2048 + oA + rowA0 + mi * 256];
#pragma unroll
            for (int ni = 0; ni < 4; ++ni)
                bv[s][ni] = *(const bf8v*)&sH[bofs0[ni] + tO + s * 7680];
        }
        __builtin_amdgcn_s_setprio(1);
#pragma unroll
        for (int s = 0; s < 2; ++s)
#pragma unroll
            for (int mi = 0; mi < 2; ++mi)
#pragma unroll
                for (int ni = 0; ni < 4; ++ni)
                    acc[mi][ni] = __builtin_amdgcn_mfma_f32_32x32x16_bf16(
                        av[s][mi], bv[s][ni], acc[mi][ni], 0, 0, 0);
        __builtin_amdgcn_s_setprio(0);

        bcur = (bcur + 1) & 3;
        ++tc;
    }

    // epilogue (32x32 C/D): col=lane&31, row=(reg&3)+8*(reg>>2)+4*ll5
    const int nfix = ng0 + wn + col;
#pragma unroll
    for (int ni = 0; ni < 4; ++ni) {
        const int n = nfix + ni * 32;
        float* ob = jb.out + (size_t)n * jb.cout_stride;
#pragma unroll
        for (int mi = 0; mi < 2; ++mi) {
            const int mb = wm + mi * 32 + 4 * ll5;
            const f16v a = acc[mi][ni];
#pragma unroll
            for (int qd = 0; qd < 4; ++qd) {
                f4v v;
                v[0] = a[qd * 4 + 0]; v[1] = a[qd * 4 + 1];
                v[2] = a[qd * 4 + 2]; v[3] = a[qd * 4 + 3];
                *(f4v*)(ob + mb + qd * 8) = v;
            }
        }
    }
}

// ------------------------------------------------------------------
// hconv: classic 2-phase stream conv (phase B: many short jobs, 576
// blocks -> better fill than the pipelined kernel for 25-tap jobs).
// N-tile 128 px (4 rows), M=128, wave tile 64x64. sH plane layout
// (4 planes x 320 cells x 8 shorts) - same conflict-free read pattern.
// ------------------------------------------------------------------
template<typename JOBS>
__global__ __launch_bounds__(256) void hconv_kernel(JOBS jobs)
{
    __shared__ unsigned short sA[8192];    // 2 x 8KB tile buffers
    __shared__ unsigned short sH[10240];   // 4 planes x 320 cells x 8 shorts
    const HJob jb = jobs.j[blockIdx.y];
    const int tid = threadIdx.x;

    const int ng0 = blockIdx.x * 128;
    const int bb = ng0 >> 10, p0 = ng0 & 1023;
    const int y0 = p0 >> 5;

    const int lane = tid & 63, wv = tid >> 6;
    const int wm = (wv & 1) << 6;
    const int wn = (wv >> 1) << 6;
    const int col = lane & 31, ll5 = lane >> 5;

    int bofs0[2];
#pragma unroll
    for (int ni = 0; ni < 2; ++ni) {
        const int ln = wn + ni * 32 + col;
        const int cell = ((ln >> 5) + 2) * 40 + (ln & 31) + 4;
        bofs0[ni] = cell * 8 + ll5 * 2560;
    }

    f16v acc[2][2];
#pragma unroll
    for (int i = 0; i < 2; ++i)
#pragma unroll
        for (int j = 0; j < 2; ++j) acc[i][j] = (f16v)0.f;

    const HSeg sg = jb.s;
    const unsigned short* inb = sg.in + ((size_t)bb << (10 + sg.cl));
    const unsigned short* wptr = jb.wt;
    int buf = 0;
    bool first = true;
    for (int ch = 0; ch < sg.nch; ++ch) {
        const int c0 = sg.c0 + ch * 32;
        // stage halo: 1280 slots of 16B (320 cells x 4 octs), 5/thread
#pragma unroll
        for (int k = 0; k < 5; ++k) {
            const int s = tid + k * 256;
            const int r = s / 160;
            const int rem = s - r * 160;
            const int cc = rem >> 2, G = rem & 3;
            const int y = y0 + r - 2, x = cc - 4;
            const bool okv = ((unsigned)y < 32u) & ((unsigned)x < 32u);
            const int yc = okv ? y : 0, xc = okv ? x : 0;
            bf8v v = *(const bf8v*)(inb + ((((yc << 5) + xc)) << sg.cl) + c0 + G * 8);
            if (!okv) v = (bf8v)(short)0;
            *(bf8v*)&sH[(G * 320 + r * 40 + cc) * 8] = v;
        }
        if (first) {
            GLDS(wptr + tid * 8,         &sA[tid * 8]);
            GLDS(wptr + (tid + 256) * 8, &sA[(tid + 256) * 8]);
            wptr += 4096;
            first = false;
        }
        __syncthreads();
        for (int t = 0; t < sg.ntaps; ++t) {
            // prefetch next tile into buf^1
            GLDS(wptr + tid * 8,         &sA[(buf ^ 1) * 4096 + tid * 8]);
            GLDS(wptr + (tid + 256) * 8, &sA[(buf ^ 1) * 4096 + (tid + 256) * 8]);
            wptr += 4096;
            int tO = 0;
            if (sg.five) {
                const int tap = sg.tap0 + t;
                const int t5 = (tap * 52) >> 8;
                tO = ((t5 - 2) * 40 + (tap - t5 * 5 - 2)) * 8;
            }
            const unsigned short* sAb = &sA[buf * 4096];
#pragma unroll
            for (int s = 0; s < 2; ++s) {
                const int o = s * 2 + ll5;
                bf8v av[2], bv[2];
#pragma unroll
                for (int mi = 0; mi < 2; ++mi)
                    av[mi] = *(const bf8v*)&sAb[(o * 128 + wm + mi * 32 + col) * 8];
#pragma unroll
                for (int ni = 0; ni < 2; ++ni)
                    bv[ni] = *(const bf8v*)&sH[bofs0[ni] + tO + s * 5120];
#pragma unroll
                for (int mi = 0; mi < 2; ++mi)
#pragma unroll
                    for (int ni = 0; ni < 2; ++ni)
                        acc[mi][ni] = __builtin_amdgcn_mfma_f32_32x32x16_bf16(
                            av[mi], bv[ni], acc[mi][ni], 0, 0, 0);
            }
            __syncthreads();
            buf ^= 1;
        }
    }

    // epilogue (32x32 C/D)
    const int nfix = ng0 + wn + col;
#pragma unroll
    for (int ni = 0; ni < 2; ++ni) {
        const int n = nfix + ni * 32;
        float* ob = jb.out + (size_t)n * jb.cout_stride;
#pragma unroll
        for (int mi = 0; mi < 2; ++mi) {
            const int mb = wm + mi * 32 + 4 * ll5;
            const f16v a = acc[mi][ni];
#pragma unroll
            for (int qd = 0; qd < 4; ++qd) {
                f4v v;
                v[0] = a[qd * 4 + 0]; v[1] = a[qd * 4 + 1];
                v[2] = a[qd * 4 + 2]; v[3] = a[qd * 4 + 3];
                *(f4v*)(ob + mb + qd * 8) = v;
            }
        }
    }
}

// ------------------------------------------------------------------
// packT: OIHW f32 -> linear tile stream [at][oct][row][8] bf16.
// ciMax: weights with ci >= ciMax are packed as zero (l0 x-conv pads
// Cin=16 up to a 32-ci chunk; matching halo channels are also zero).
// ------------------------------------------------------------------
__global__ __launch_bounds__(256) void packT_kernel(
    const float* __restrict__ src, unsigned short* __restrict__ dst,
    int Cin, int srcTaps, int rowOff, int ci0, int ntaps, int tap0,
    int ciMax, int total)
{
    const int idx = blockIdx.x * 256 + threadIdx.x;
    if (idx >= total) return;
    const int j = idx & 7;
    const int row = (idx >> 3) & 127;
    const int q = (idx >> 10) & 3;
    const int at = idx >> 12;
    const int ch = at / ntaps;
    const int tap = tap0 + (at - ch * ntaps);
    const int ci = ci0 + ch * 32 + q * 8 + j;
    float v = 0.f;
    if (ci < ciMax)
        v = src[((size_t)(rowOff + row) * Cin + ci) * srcTaps + tap];
    dst[idx] = f2bf(v);
}

// net (blended frame) written 32-channel-wide, upper 16 channels zero,
// so the l0 x-conv runs on the standard 32-ci stream path.
__global__ __launch_bounds__(256) void net_kernel(
    const float* __restrict__ frames, const float* __restrict__ mask,
    const float* __restrict__ xgen, unsigned short* __restrict__ net, int t)
{
    const int idx = blockIdx.x * 256 + threadIdx.x;  // 8192*32
    const int n = idx >> 5, ch = idx & 31;
    float v = 0.f;
    if (ch < 16) {
        const int b = n >> 10, p = n & 1023;
        const float fr = frames[((((size_t)b * 20 + t) << 10) + p) * 16 + ch];
        if (t < TPREV) v = fr;
        else {
            const float mk = mask[((((size_t)b * 9 + (t - TPREV)) << 10) + p) * 16 + ch];
            v = mk * fr + (1.f - mk) * xgen[(size_t)n * 16 + ch];
        }
    }
    net[idx] = f2bf(v);
}

__global__ __launch_bounds__(256) void gates_kernel(
    const float* __restrict__ preA, const float* __restrict__ preB,
    float* __restrict__ c, float* __restrict__ m,
    unsigned short* __restrict__ m_bf, unsigned short* __restrict__ mem)
{
    const int idx = blockIdx.x * 256 + threadIdx.x;  // 8192*128
    const int n = idx >> 7, ch = idx & 127;
    const float* pa = preA + (size_t)n * 896 + ch;
    const float* pb = preB + (size_t)n * 896 + ch;
    const float i_ = pa[0]   + pb[0];
    const float f_ = pa[128] + pb[128];
    const float g_ = pa[256] + pb[256];
    const float ip = pa[384] + pb[384];
    const float fp = pa[512] + pb[512];
    const float gp = pa[640] + pb[640];
    const float cn = sigmoidf_(f_ + 1.f) * c[idx] + sigmoidf_(i_) * tanhf(g_);
    const float mn = sigmoidf_(fp + 1.f) * m[idx] + sigmoidf_(ip) * tanhf(gp);
    c[idx] = cn;
    m[idx] = mn;
    m_bf[idx] = f2bf(mn);
    mem[(size_t)n * 256 + ch] = f2bf(cn);
    mem[(size_t)n * 256 + 128 + ch] = f2bf(mn);
}

__global__ __launch_bounds__(256) void hout_kernel(
    const float* __restrict__ preA, const float* __restrict__ preB,
    const float* __restrict__ opart, const float* __restrict__ lconv,
    unsigned short* __restrict__ h)
{
    const int idx = blockIdx.x * 256 + threadIdx.x;  // 8192*128
    const int n = idx >> 7, ch = idx & 127;
    float oc = preA[(size_t)n * 896 + 768 + ch] + preB[(size_t)n * 896 + 768 + ch];
#pragma unroll
    for (int j = 0; j < 8; ++j) oc += opart[idx + (size_t)j * 1048576];
    h[idx] = f2bf(sigmoidf_(oc) * tanhf(lconv[idx]));
}

__global__ __launch_bounds__(256) void wout_kernel(
    const unsigned short* __restrict__ h3, const float* __restrict__ wo,
    float* __restrict__ xgen, float* __restrict__ out, int t)
{
    const int idx = blockIdx.x * 256 + threadIdx.x;  // 8192*16
    const int n = idx >> 4, ch = idx & 15;
    const int b = n >> 10, p = n & 1023;
    const unsigned short* hr = h3 + (size_t)n * 128;
    const float* wr = wo + ch * 128;
    float acc = 0.f;
#pragma unroll 8
    for (int ci = 0; ci < 128; ++ci)
        acc = fmaf(bf2f(hr[ci]), wr[ci], acc);
    xgen[idx] = acc;
    out[((((size_t)b * TT + t) << 10) + p) * 16 + ch] = acc;
}

extern "C" void kernel_launch(void* const* d_in, const int* in_sizes, int n_in,
                              void* d_out, int out_size, void* d_ws, size_t ws_size,
                              hipStream_t stream)
{
    const float* frames = (const float*)d_in[0];
    const float* mask   = (const float*)d_in[1];
    const float* Wx0    = (const float*)d_in[2];
    const float* Wx     = (const float*)d_in[3];
    const float* Wh     = (const float*)d_in[4];
    const float* Wm     = (const float*)d_in[5];
    const float* Wo     = (const float*)d_in[6];
    const float* Wl     = (const float*)d_in[7];
    const float* Wout   = (const float*)d_in[8];
    float* out = (float*)d_out;

    char* base = (char*)d_ws;
    size_t off = 0;
    auto take = [&](size_t bytes) -> char* {
        char* p = base + off;
        off = (off + bytes + 255) & ~(size_t)255;
        return p;
    };
    // ---- zero-init region ----
    float* c0            = (float*)take(4ull * 1048576 * 4);
    float* m32           = (float*)take((size_t)1048576 * 4);
    unsigned short* hbf  = (unsigned short*)take(4ull * 1048576 * 2);
    unsigned short* mbf  = (unsigned short*)take((size_t)1048576 * 2);
    const size_t zbytes = off;
    // ---- working buffers ----
    float* xgen          = (float*)take((size_t)131072 * 4);
    float* preA          = (float*)take((size_t)8192 * 896 * 4);
    float* preB          = (float*)take((size_t)8192 * 896 * 4);
    float* lconv         = (float*)take((size_t)1048576 * 4);
    float* opart         = (float*)take(8ull * 1048576 * 4);
    unsigned short* net  = (unsigned short*)take((size_t)262144 * 2);   // [8192][32]
    unsigned short* mem  = (unsigned short*)take((size_t)2097152 * 2);
    // ---- packed weights (tile streams; +4096 el pad) ----
    unsigned short* pa0xT = (unsigned short*)take(((size_t)7 * 25 * 4096 + 4096) * 2);
    unsigned short* paT0 = (unsigned short*)take(((size_t)7 * 100 * 4096 + 4096) * 2);
    unsigned short* paT1 = (unsigned short*)take(((size_t)7 * 200 * 4096 + 4096) * 2);
    unsigned short* paT2 = (unsigned short*)take(((size_t)7 * 200 * 4096 + 4096) * 2);
    unsigned short* paT3 = (unsigned short*)take(((size_t)7 * 200 * 4096 + 4096) * 2);
    unsigned short* paT[4] = { paT0, paT1, paT2, paT3 };
    unsigned short* oT   = (unsigned short*)take((4ull * 200 * 4096 + 4096) * 2);
    unsigned short* lT   = (unsigned short*)take((4ull * 8 * 4096 + 4096) * 2);

    hipMemsetAsync(d_ws, 0, zbytes, stream);

    auto packT = [&](const float* s, unsigned short* d, int Cin, int srcTaps,
                     int rowOff, int ci0, int nch, int ntaps, int tap0, int ciMax) {
        const int total = nch * ntaps * 4096;
        packT_kernel<<<(total + 255) / 256, 256, 0, stream>>>(
            s, d, Cin, srcTaps, rowOff, ci0, ntaps, tap0, ciMax, total);
    };
    const int CIMAXBIG = 1 << 30;
    for (int g = 0; g < 7; ++g) {
        // l0 x-conv: Cin=16 zero-padded to one 32-ci chunk (25 tiles/group)
        packT(Wx0, pa0xT + (size_t)g * 25 * 4096, 16, 25, g * 128, 0, 1, 25, 0, 16);
        const float* hm0 = (g < 3) ? (Wh + (size_t)g * 128 * 128 * 25)
                         : (g == 6) ? (Wh + (size_t)384 * 128 * 25)
                                    : (Wm + (size_t)(g - 3) * 128 * 128 * 25);
        packT(hm0, paT0 + (size_t)g * 100 * 4096, 128, 25, 0, 0, 4, 25, 0, CIMAXBIG);
        for (int l = 1; l < 4; ++l) {
            packT(Wx + (size_t)(l - 1) * 896 * 128 * 25,
                  paT[l] + (size_t)g * 200 * 4096, 128, 25, g * 128, 0, 4, 25, 0, CIMAXBIG);
            const float* hmsrc = (g < 3) ? (Wh + ((size_t)l * 512 + g * 128) * 128 * 25)
                               : (g == 6) ? (Wh + ((size_t)l * 512 + 384) * 128 * 25)
                                          : (Wm + ((size_t)l * 384 + (g - 3) * 128) * 128 * 25);
            packT(hmsrc, paT[l] + ((size_t)g * 200 + 100) * 4096, 128, 25, 0, 0, 4, 25, 0, CIMAXBIG);
        }
    }
    for (int l = 0; l < 4; ++l) {
        packT(Wo + (size_t)l * 128 * 256 * 25, oT + (size_t)l * 200 * 4096,
              256, 25, 0, 0, 8, 25, 0, CIMAXBIG);
        packT(Wl + (size_t)l * 128 * 256, lT + (size_t)l * 8 * 4096,
              256, 1, 0, 0, 8, 1, 0, CIMAXBIG);
    }

    for (int t = 0; t < TT; ++t) {
        net_kernel<<<1024, 256, 0, stream>>>(frames, mask, xgen, net, t);
        for (int l = 0; l < 4; ++l) {
            unsigned short* hl = hbf + (size_t)l * 1048576;
            // ---- phase A: one hconvA dispatch of 14 jobs ----
            HJobs14 JA{};
            if (l == 0) {
                // interleave short x-jobs (25 taps) with long hm-jobs (100
                // taps) so each XCD-cluster gets a balanced mix.
                for (int g = 0; g < 7; ++g) {
                    const unsigned short* hmsrc = (g < 3 || g == 6) ? hl : mbf;
                    JA.j[2 * g] = HJob{ pa0xT + (size_t)g * 25 * 4096, preA + g * 128,
                                        896, 0, HSeg{ net, 5, 0, 1, 0, 25, 1 } };
                    JA.j[2 * g + 1] = HJob{ paT0 + (size_t)g * 100 * 4096, preB + g * 128,
                                            896, 0, HSeg{ hmsrc, 7, 0, 4, 0, 25, 1 } };
                }
            } else {
                for (int g = 0; g < 7; ++g) {
                    const unsigned short* hmsrc = (g < 3 || g == 6) ? hl : mbf;
                    JA.j[g] = HJob{ paT[l] + (size_t)g * 200 * 4096, preA + g * 128,
                                    896, 0, HSeg{ hbf + (size_t)(l - 1) * 1048576, 7, 0, 4, 0, 25, 1 } };
                    JA.j[7 + g] = HJob{ paT[l] + ((size_t)g * 200 + 100) * 4096, preB + g * 128,
                                        896, 0, HSeg{ hmsrc, 7, 0, 4, 0, 25, 1 } };
                }
            }
            hconvA_kernel<HJobs14><<<dim3(32, 14), 256, 0, stream>>>(JA);

            gates_kernel<<<4096, 256, 0, stream>>>(preA, preB,
                c0 + (size_t)l * 1048576, m32, mbf, mem);

            // ---- phase B: o-conv split by ci-chunk x8 + lconv (classic kernel)
            HJobs9 JB{};
            for (int jj = 0; jj < 8; ++jj)
                JB.j[jj] = HJob{ oT + ((size_t)l * 200 + jj * 25) * 4096,
                                 opart + (size_t)jj * 1048576, 128, 0,
                                 HSeg{ mem, 8, jj * 32, 1, 0, 25, 1 } };
            JB.j[8] = HJob{ lT + (size_t)l * 8 * 4096, lconv, 128, 0,
                            HSeg{ mem, 8, 0, 8, 0, 1, 0 } };
            hconv_kernel<HJobs9><<<dim3(64, 9), 256, 0, stream>>>(JB);

            hout_kernel<<<4096, 256, 0, stream>>>(preA, preB, opart, lconv, hl);
        }
        wout_kernel<<<512, 256, 0, stream>>>(hbf + (size_t)3 * 1048576, Wout, xgen, out, t);
    }
}